// Round 2
// baseline (522.690 us; speedup 1.0000x reference)
//
#include <hip/hip_runtime.h>
#include <hip/hip_bf16.h>

using u16 = unsigned short;
using u32 = unsigned int;

#define NNODES 50000
#define NEDGE  200000
#define DEGCAP 64

// ---------- bf16 helpers ----------
__device__ __forceinline__ float blo2f(u32 u) { u32 v = u << 16; float f; __builtin_memcpy(&f, &v, 4); return f; }
__device__ __forceinline__ float bhi2f(u32 u) { u32 v = u & 0xffff0000u; float f; __builtin_memcpy(&f, &v, 4); return f; }
__device__ __forceinline__ float b2f(u16 u) { u32 v = ((u32)u) << 16; float f; __builtin_memcpy(&f, &v, 4); return f; }
__device__ __forceinline__ u16 f2b(float f) {
  __hip_bfloat16 h = __float2bfloat16(f);   // RNE
  u16 r; __builtin_memcpy(&r, &h, 2); return r;
}
__device__ __forceinline__ float gelu_exact(float x) {
  return 0.5f * x * (1.f + erff(x * 0.70710678118654752f));
}

typedef __bf16 bh8 __attribute__((ext_vector_type(8)));
typedef float f32x4 __attribute__((ext_vector_type(4)));

__device__ __forceinline__ bh8 cvt8(const float* p) {
  const float4 a = *(const float4*)p;
  const float4 b = *(const float4*)(p + 4);
  bh8 r;
  r[0] = (__bf16)a.x; r[1] = (__bf16)a.y; r[2] = (__bf16)a.z; r[3] = (__bf16)a.w;
  r[4] = (__bf16)b.x; r[5] = (__bf16)b.y; r[6] = (__bf16)b.z; r[7] = (__bf16)b.w;
  return r;
}

struct GArg { const void* A; const u16* B; const float* bias; void* C; };

// ---------- LDS-free direct-fragment GEMM: C[M,256] = A[M,256] @ B^T + bias ----------
// B stored [n][k] bf16. No __syncthreads anywhere: fragments load straight from
// global (coalesced 16B/lane; B is L1/L2-hot), compiler pipelines loads vs MFMA.
// MODE 0: A fp32 (cvt in regs), relu, bf16 out.
// MODE 1: A bf16, bias only, bf16 out.
// MODE 2: A bf16, skip-blend with hbl, bf16 out.
template <int MODE>
__launch_bounds__(256)
__global__ void gemm_d(GArg g0, GArg g1, GArg g2, int M,
                       const u16* __restrict__ hbl, const float* __restrict__ skipv)
{
  GArg ga = (blockIdx.z == 0) ? g0 : ((blockIdx.z == 1) ? g1 : g2);
  const int m0 = blockIdx.x * 128;
  const int n0 = blockIdx.y * 128;
  const int t = threadIdx.x;
  const int lane = t & 63;
  const int wave = t >> 6;
  const int wm = (wave & 1) * 64;
  const int wn = (wave >> 1) * 64;
  const int lr = lane & 15;
  const int lq = lane >> 4;

  const u16* brow[4];
#pragma unroll
  for (int f = 0; f < 4; ++f)
    brow[f] = ga.B + (size_t)(n0 + wn + f * 16 + lr) * 256 + lq * 8;

  const float* arow_f[4];
  const u16*   arow_h[4];
#pragma unroll
  for (int f = 0; f < 4; ++f) {
    int r = m0 + wm + f * 16 + lr; if (r >= M) r = M - 1;  // clamp; never stored
    if (MODE == 0) arow_f[f] = (const float*)ga.A + (size_t)r * 256 + lq * 8;
    else           arow_h[f] = (const u16*)ga.A + (size_t)r * 256 + lq * 8;
  }

  f32x4 acc[4][4];
  const f32x4 vzero = {0.f, 0.f, 0.f, 0.f};
#pragma unroll
  for (int i = 0; i < 4; ++i)
#pragma unroll
    for (int j = 0; j < 4; ++j) acc[i][j] = vzero;

#pragma unroll
  for (int ks = 0; ks < 8; ++ks) {      // K = 8 × 32
    bh8 af[4], bf[4];
#pragma unroll
    for (int f = 0; f < 4; ++f) {
      if (MODE == 0) af[f] = cvt8(arow_f[f] + ks * 32);
      else           af[f] = *(const bh8*)(arow_h[f] + ks * 32);
      bf[f] = *(const bh8*)(brow[f] + ks * 32);
    }
#pragma unroll
    for (int fm = 0; fm < 4; ++fm)
#pragma unroll
      for (int fn = 0; fn < 4; ++fn)
        acc[fm][fn] = __builtin_amdgcn_mfma_f32_16x16x32_bf16(af[fm], bf[fn], acc[fm][fn], 0, 0, 0);
  }

  float beta = 0.f, omb = 0.f;
  if (MODE == 2) { beta = 1.f / (1.f + __expf(-skipv[0])); omb = 1.f - beta; }
#pragma unroll
  for (int fn = 0; fn < 4; ++fn) {
    const int col = n0 + wn + fn * 16 + lr;       // C/D: col = lane&15
    const float bv = ga.bias[col];
#pragma unroll
    for (int fm = 0; fm < 4; ++fm) {
#pragma unroll
      for (int r = 0; r < 4; ++r) {
        const int row = m0 + wm + fm * 16 + lq * 4 + r;  // C/D: row = quad*4 + reg
        if (row < M) {
          float v = acc[fm][fn][r] + bv;
          if (MODE == 0) v = fmaxf(v, 0.f);
          if (MODE == 2) {
            const float hv = b2f(hbl[(size_t)row * 256 + col]);
            v = beta * v + omb * hv;
          }
          ((u16*)ga.C)[(size_t)row * 256 + col] = f2b(v);
        }
      }
    }
  }
}

// ---------- weight prep: transpose->bf16, fold a_rel/m_rel into k/v weights, out_w^T ----------
__global__ void prep_w_k(const float* __restrict__ lin_w, const float* __restrict__ q_w,
                         const float* __restrict__ a_w, const float* __restrict__ k_w,
                         const float* __restrict__ v_w, const float* __restrict__ k_b,
                         const float* __restrict__ v_b, const float* __restrict__ a_rel,
                         const float* __restrict__ m_rel, const float* __restrict__ out_w,
                         u16* __restrict__ lin0T, u16* __restrict__ lin1T,
                         u16* __restrict__ qT, u16* __restrict__ aT,
                         u16* __restrict__ kfT, u16* __restrict__ vfT,
                         u16* __restrict__ owT,
                         float* __restrict__ bkf, float* __restrict__ bvf)
{
  const int tid = blockIdx.x * 256 + threadIdx.x;  // 0..65535 ; out layout [n][k]
  const int nn = tid >> 8, kk = tid & 255;
  switch (blockIdx.y) {
    case 0: lin0T[tid] = f2b(lin_w[kk * 256 + nn]); break;
    case 1: lin1T[tid] = f2b(lin_w[65536 + kk * 256 + nn]); break;
    case 2: qT[tid] = f2b(q_w[65536 + kk * 256 + nn]); break;
    case 3: aT[tid] = f2b(a_w[65536 + kk * 256 + nn]); break;
    case 4: {
      const int h = nn >> 5, e = nn & 31;
      float s = 0.f;
      for (int d = 0; d < 32; ++d) s += k_w[kk * 256 + h * 32 + d] * a_rel[(h * 32 + d) * 32 + e];
      kfT[tid] = f2b(s);
      if (kk == 0) {
        float sb = 0.f;
        for (int d = 0; d < 32; ++d) sb += k_b[h * 32 + d] * a_rel[(h * 32 + d) * 32 + e];
        bkf[nn] = sb;
      }
      break;
    }
    case 5: {
      const int h = nn >> 5, e = nn & 31;
      float s = 0.f;
      for (int d = 0; d < 32; ++d) s += v_w[kk * 256 + h * 32 + d] * m_rel[(h * 32 + d) * 32 + e];
      vfT[tid] = f2b(s);
      if (kk == 0) {
        float sb = 0.f;
        for (int d = 0; d < 32; ++d) sb += v_b[h * 32 + d] * m_rel[(h * 32 + d) * 32 + e];
        bvf[nn] = sb;
      }
      break;
    }
    default:
      if (tid < 4096) owT[tid] = f2b(out_w[kk * 16 + nn]);  // owT[n][k], n<16
      break;
  }
}

// ---------- bucket-CSR build for edge type 0 (src type 0 -> dst type 1) ----------
__global__ void scatter_k(const int* __restrict__ ei, int* __restrict__ cnt, int* __restrict__ srcl) {
  const int e = blockIdx.x * 256 + threadIdx.x;
  if (e >= NEDGE) return;
  const int src = ei[e];          // edge_index[0][0][e]
  const int dst = ei[NEDGE + e];  // edge_index[0][1][e]
  if ((unsigned)dst >= NNODES || (unsigned)src >= NNODES) return;
  const int pos = atomicAdd(&cnt[dst], 1);
  if (pos < DEGCAP) srcl[(size_t)dst * DEGCAP + pos] = src;
}

// ---------- fused attention softmax + aggregation + GELU; one wave per dst node ----------
__global__ void edge_agg_k(const u16* __restrict__ qb, const u16* __restrict__ krel,
                           const u16* __restrict__ vrel, const int* __restrict__ cnt,
                           const int* __restrict__ srcl, const float* __restrict__ prel,
                           u16* __restrict__ g)
{
  const int node = (blockIdx.x * blockDim.x + threadIdx.x) >> 6;
  if (node >= NNODES) return;
  const int lane = threadIdx.x & 63;
  const int hh = lane >> 3;                 // head
  const int off = hh * 32 + (lane & 7) * 4; // 4 dims per lane
  const float scale = prel[hh] * 0.17677669529663687f;  // p_rel[0][h] / sqrt(32)
  const uint2 qv = *(const uint2*)(qb + (size_t)node * 256 + off);
  const float q0 = blo2f(qv.x) * scale, q1 = bhi2f(qv.x) * scale;
  const float q2 = blo2f(qv.y) * scale, q3 = bhi2f(qv.y) * scale;
  int dg = cnt[node]; if (dg > DEGCAP) dg = DEGCAP;
  const int* sl = srcl + (size_t)node * DEGCAP;
  float den = 0.f, a0 = 0.f, a1 = 0.f, a2 = 0.f, a3 = 0.f;
  for (int i = 0; i < dg; ++i) {
    const int src = sl[i];
    const uint2 kv = *(const uint2*)(krel + (size_t)src * 256 + off);
    float p = q0 * blo2f(kv.x) + q1 * bhi2f(kv.x) + q2 * blo2f(kv.y) + q3 * bhi2f(kv.y);
    p += __shfl_xor(p, 1);
    p += __shfl_xor(p, 2);
    p += __shfl_xor(p, 4);           // 8-lane head-group reduce
    const float ex = __expf(p);      // no max-subtraction: |alpha| is O(1) here
    const uint2 vv = *(const uint2*)(vrel + (size_t)src * 256 + off);
    den += ex;
    a0 += ex * blo2f(vv.x); a1 += ex * bhi2f(vv.x);
    a2 += ex * blo2f(vv.y); a3 += ex * bhi2f(vv.y);
  }
  float r0 = 0.f, r1 = 0.f, r2 = 0.f, r3 = 0.f;
  if (dg > 0) {
    const float inv = 1.f / den;
    r0 = gelu_exact(a0 * inv); r1 = gelu_exact(a1 * inv);
    r2 = gelu_exact(a2 * inv); r3 = gelu_exact(a3 * inv);
  }
  uint2 gv;
  gv.x = (u32)f2b(r0) | ((u32)f2b(r1) << 16);
  gv.y = (u32)f2b(r2) | ((u32)f2b(r3) << 16);
  *(uint2*)(g + (size_t)node * 256 + off) = gv;
}

// ---------- final GEMM via MFMA: out[M,16] = o[M,256] @ owT^T + out_b, fp32 out ----------
__launch_bounds__(256)
__global__ void out_mfma_k(const u16* __restrict__ o, const u16* __restrict__ owT,
                           const float* __restrict__ ob, float* __restrict__ out, int M)
{
  const int t = threadIdx.x;
  const int lane = t & 63;
  const int wave = t >> 6;
  const int lr = lane & 15;
  const int lq = lane >> 4;
  const int r0 = blockIdx.x * 128 + wave * 32;

  const u16* brow = owT + (size_t)lr * 256 + lq * 8;   // n = lr (0..15)
  const u16* arow[2];
#pragma unroll
  for (int fm = 0; fm < 2; ++fm) {
    int r = r0 + fm * 16 + lr; if (r >= M) r = M - 1;
    arow[fm] = o + (size_t)r * 256 + lq * 8;
  }
  f32x4 acc[2];
  acc[0] = (f32x4){0.f, 0.f, 0.f, 0.f};
  acc[1] = (f32x4){0.f, 0.f, 0.f, 0.f};
#pragma unroll
  for (int ks = 0; ks < 8; ++ks) {
    const bh8 b8 = *(const bh8*)(brow + ks * 32);
#pragma unroll
    for (int fm = 0; fm < 2; ++fm)
      acc[fm] = __builtin_amdgcn_mfma_f32_16x16x32_bf16(*(const bh8*)(arow[fm] + ks * 32), b8, acc[fm], 0, 0, 0);
  }
  const float bv = ob[lr];
#pragma unroll
  for (int fm = 0; fm < 2; ++fm)
#pragma unroll
    for (int r = 0; r < 4; ++r) {
      const int row = r0 + fm * 16 + lq * 4 + r;
      if (row < M) out[(size_t)row * 16 + lr] = acc[fm][r] + bv;
    }
}

extern "C" void kernel_launch(void* const* d_in, const int* in_sizes, int n_in,
                              void* d_out, int out_size, void* d_ws, size_t ws_size,
                              hipStream_t stream)
{
  const float* x     = (const float*)d_in[0];
  const int*   ei    = (const int*)d_in[1];
  const float* lin_w = (const float*)d_in[2];
  const float* lin_b = (const float*)d_in[3];
  const float* k_w   = (const float*)d_in[4];
  const float* k_b   = (const float*)d_in[5];
  const float* q_w   = (const float*)d_in[6];
  const float* q_b   = (const float*)d_in[7];
  const float* v_w   = (const float*)d_in[8];
  const float* v_b   = (const float*)d_in[9];
  const float* a_w   = (const float*)d_in[10];
  const float* a_b   = (const float*)d_in[11];
  const float* skipv = (const float*)d_in[12];
  const float* a_rel = (const float*)d_in[13];
  const float* m_rel = (const float*)d_in[14];
  const float* p_rel = (const float*)d_in[15];
  const float* out_w = (const float*)d_in[16];
  const float* out_b = (const float*)d_in[17];
  char* ws = (char*)d_ws;

  // workspace layout (bytes); h0 region reused for obuf after it dies
  u16*  h0    = (u16*)(ws + 0);              // 25.6 MB (dead after GEMM2)
  u16*  h1    = (u16*)(ws + 25600000);       // 25.6 MB (alive till blend)
  u16*  qb    = (u16*)(ws + 51200000);
  u16*  gbuf  = (u16*)(ws + 76800000);
  u16*  krel  = (u16*)(ws + 102400000);
  u16*  vrel  = (u16*)(ws + 128000000);
  u16*  obuf  = (u16*)(ws + 0);              // reuse h0 region (bf16 o)
  char* W     = ws + 153600000;
  u16*  lin0T = (u16*)(W + 0);
  u16*  lin1T = (u16*)(W + 131072);
  u16*  qT    = (u16*)(W + 2 * 131072);
  u16*  aT    = (u16*)(W + 3 * 131072);
  u16*  kfT   = (u16*)(W + 4 * 131072);
  u16*  vfT   = (u16*)(W + 5 * 131072);
  u16*  owT   = (u16*)(W + 6 * 131072);      // 8 KB used
  float* bkf  = (float*)(W + 6 * 131072 + 8192);
  float* bvf  = (float*)(W + 6 * 131072 + 9216);
  int*  cnt   = (int*)(W + 6 * 131072 + 10240);
  int*  srcl  = (int*)(W + 6 * 131072 + 10240 + 200000);   // 12.8 MB

  hipMemsetAsync(cnt, 0, NNODES * sizeof(int), stream);
  prep_w_k<<<dim3(256, 7), 256, 0, stream>>>(lin_w, q_w, a_w, k_w, v_w, k_b, v_b,
                                             a_rel, m_rel, out_w,
                                             lin0T, lin1T, qT, aT, kfT, vfT, owT, bkf, bvf);
  scatter_k<<<(NEDGE + 255) / 256, 256, 0, stream>>>(ei, cnt, srcl);

  {  // h[t] = relu(x[t] @ lin_w[t] + lin_b[t]) ; fp32 A converted in-kernel
    GArg a0{x, lin0T, lin_b, h0};
    GArg a1{x + (size_t)NNODES * 256, lin1T, lin_b + 256, h1};
    gemm_d<0><<<dim3(391, 2, 2), 256, 0, stream>>>(a0, a1, a0, NNODES, nullptr, nullptr);
  }
  {  // q1 = h1@q_w1+b ; krel = h0@(k_w0*a_rel0)+b' ; vrel = h0@(v_w0*m_rel0)+b'
    GArg a0{h1, qT, q_b + 256, qb};
    GArg a1{h0, kfT, bkf, krel};
    GArg a2{h0, vfT, bvf, vrel};
    gemm_d<1><<<dim3(391, 2, 3), 256, 0, stream>>>(a0, a1, a2, NNODES, nullptr, nullptr);
  }
  edge_agg_k<<<12500, 256, 0, stream>>>(qb, krel, vrel, cnt, srcl, p_rel, gbuf);
  {  // o = beta*(gelu(agg)@a_w1 + a_b1) + (1-beta)*h1, bf16 out
    GArg a0{gbuf, aT, a_b + 256, obuf};
    gemm_d<2><<<dim3(391, 2, 1), 256, 0, stream>>>(a0, a0, a0, NNODES, h1, skipv + 1);
  }
  out_mfma_k<<<391, 256, 0, stream>>>(obuf, owT, out_b, (float*)d_out, NNODES);
}

// Round 3
// 470.016 us; speedup vs baseline: 1.1121x; 1.1121x over previous
//
#include <hip/hip_runtime.h>
#include <hip/hip_bf16.h>

using u16 = unsigned short;
using u32 = unsigned int;

#define NNODES 50000
#define NEDGE  200000
#define DEGCAP 64
#define NT     3125   // 50000 / 16 row-tiles

// ---------- bf16 helpers ----------
__device__ __forceinline__ float blo2f(u32 u) { u32 v = u << 16; float f; __builtin_memcpy(&f, &v, 4); return f; }
__device__ __forceinline__ float bhi2f(u32 u) { u32 v = u & 0xffff0000u; float f; __builtin_memcpy(&f, &v, 4); return f; }
__device__ __forceinline__ float b2f(u16 u) { u32 v = ((u32)u) << 16; float f; __builtin_memcpy(&f, &v, 4); return f; }
__device__ __forceinline__ u16 f2b(float f) {
  __hip_bfloat16 h = __float2bfloat16(f);   // RNE
  u16 r; __builtin_memcpy(&r, &h, 2); return r;
}
__device__ __forceinline__ float gelu_exact(float x) {
  return 0.5f * x * (1.f + erff(x * 0.70710678118654752f));
}

typedef __bf16 bh8 __attribute__((ext_vector_type(8)));
typedef float f32x4 __attribute__((ext_vector_type(4)));

__device__ __forceinline__ bh8 cvt8(const float4 a, const float4 b) {
  bh8 r;
  r[0] = (__bf16)a.x; r[1] = (__bf16)a.y; r[2] = (__bf16)a.z; r[3] = (__bf16)a.w;
  r[4] = (__bf16)b.x; r[5] = (__bf16)b.y; r[6] = (__bf16)b.z; r[7] = (__bf16)b.w;
  return r;
}

struct GArg { const void* A; const u16* B; const float* bias; void* C; };

// ---------- streaming GEMM: C[50000,256] = A[50000,256] @ B^T + bias ----------
// B stored [n][k] bf16, register-resident per wave (32-col strip, 64 VGPR).
// Grid-stride loop over 16-row tiles; A-fragment slots refilled IN PLACE right
// after the MFMA that consumes them (one-tile lookahead, no barriers, no vmcnt(0)).
// Epilogue goes through a per-wave private LDS patch for fully-coalesced stores.
// MODE 0: A fp32 (cvt in regs), relu, bf16 out.
// MODE 1: A bf16, bias only, bf16 out.
// MODE 2: A bf16, skip-blend with hbl, bf16 out.
template <int MODE>
__launch_bounds__(256, MODE == 0 ? 2 : 3)
__global__ void gemm_s(GArg g0, GArg g1, GArg g2,
                       const u16* __restrict__ hbl, const float* __restrict__ skipv)
{
  GArg ga = (blockIdx.z == 0) ? g0 : ((blockIdx.z == 1) ? g1 : g2);
  const int t0 = blockIdx.x;
  const int ts = gridDim.x;
  const int tid = threadIdx.x;
  const int lane = tid & 63;
  const int wave = tid >> 6;
  const int lr = lane & 15;
  const int lq = lane >> 4;
  const int colbase = blockIdx.y * 128 + wave * 32;

  __shared__ u16 eld[4 * 640];          // per-wave 16 x (32 used of 40) u16 patch
  u16* wl = eld + wave * 640;

  // --- preload B strip (K=256 for 32 cols) into registers ---
  bh8 B0[8], B1[8];
  {
    const u16* bp0 = ga.B + (size_t)(colbase + lr) * 256 + lq * 8;
    const u16* bp1 = bp0 + 16 * 256;
#pragma unroll
    for (int ks = 0; ks < 8; ++ks) {
      B0[ks] = *(const bh8*)(bp0 + ks * 32);
      B1[ks] = *(const bh8*)(bp1 + ks * 32);
    }
  }
  const float bias0 = ga.bias[colbase + lr];
  const float bias1 = ga.bias[colbase + 16 + lr];
  float beta = 0.f, omb = 0.f;
  if (MODE == 2) { beta = 1.f / (1.f + __expf(-skipv[0])); omb = 1.f - beta; }

  // --- A fragment pointers: lane-fixed offset, advance by tile ---
  const size_t loff = (size_t)lr * 256 + lq * 8;   // elements
  const float* af = (MODE == 0) ? (const float*)ga.A + (size_t)t0 * 4096 + loff : nullptr;
  const u16*   ah = (MODE != 0) ? (const u16*)ga.A + (size_t)t0 * 4096 + loff : nullptr;
  const size_t tstep = (size_t)ts * 4096;

  // --- prime slots for tile t0 ---
  float4 ar[8][2];
  bh8    ab[8];
#pragma unroll
  for (int ks = 0; ks < 8; ++ks) {
    if (MODE == 0) {
      ar[ks][0] = *(const float4*)(af + ks * 32);
      ar[ks][1] = *(const float4*)(af + ks * 32 + 4);
    } else {
      ab[ks] = *(const bh8*)(ah + ks * 32);
    }
  }

  for (int t = t0; t < NT; t += ts) {
    // advance load pointer to tile t+ts (clamped in-bounds; extra loads unused)
    if (t + ts < NT) { if (MODE == 0) af += tstep; else ah += tstep; }

    f32x4 acc0 = {0.f, 0.f, 0.f, 0.f};
    f32x4 acc1 = {0.f, 0.f, 0.f, 0.f};
#pragma unroll
    for (int ks = 0; ks < 8; ++ks) {
      bh8 a8;
      if (MODE == 0) a8 = cvt8(ar[ks][0], ar[ks][1]);
      else           a8 = ab[ks];
      acc0 = __builtin_amdgcn_mfma_f32_16x16x32_bf16(a8, B0[ks], acc0, 0, 0, 0);
      acc1 = __builtin_amdgcn_mfma_f32_16x16x32_bf16(a8, B1[ks], acc1, 0, 0, 0);
      // in-place refill of the just-consumed slot with the next tile's data
      if (MODE == 0) {
        ar[ks][0] = *(const float4*)(af + ks * 32);
        ar[ks][1] = *(const float4*)(af + ks * 32 + 4);
      } else {
        ab[ks] = *(const bh8*)(ah + ks * 32);
      }
    }

    // --- epilogue: acc -> per-wave LDS patch -> coalesced 16B/lane store ---
#pragma unroll
    for (int r = 0; r < 4; ++r) {
      float v0 = acc0[r] + bias0;
      float v1 = acc1[r] + bias1;
      if (MODE == 0) { v0 = fmaxf(v0, 0.f); v1 = fmaxf(v1, 0.f); }
      wl[(lq * 4 + r) * 40 + lr]      = f2b(v0);
      wl[(lq * 4 + r) * 40 + 16 + lr] = f2b(v1);
    }
    const int rrow = lane >> 2, rseg = lane & 3;
    const uint4 pv = *(const uint4*)(wl + rrow * 40 + rseg * 8);  // lgkm wait auto
    const size_t cb = ((size_t)t * 16 + rrow) * 256 + colbase + rseg * 8;
    if (MODE == 2) {
      const uint4 hv = *(const uint4*)(hbl + cb);
      uint4 ov;
      {
        const u32 p[4] = {pv.x, pv.y, pv.z, pv.w};
        const u32 h[4] = {hv.x, hv.y, hv.z, hv.w};
        u32 o[4];
#pragma unroll
        for (int j = 0; j < 4; ++j) {
          const float a0 = blo2f(p[j]), a1 = bhi2f(p[j]);
          const float h0 = blo2f(h[j]), h1 = bhi2f(h[j]);
          o[j] = (u32)f2b(beta * a0 + omb * h0) | ((u32)f2b(beta * a1 + omb * h1) << 16);
        }
        ov.x = o[0]; ov.y = o[1]; ov.z = o[2]; ov.w = o[3];
      }
      *(uint4*)((u16*)ga.C + cb) = ov;
    } else {
      *(uint4*)((u16*)ga.C + cb) = pv;
    }
  }
}

// ---------- weight prep: transpose->bf16, fold a_rel/m_rel into k/v weights, out_w^T ----------
__global__ void prep_w_k(const float* __restrict__ lin_w, const float* __restrict__ q_w,
                         const float* __restrict__ a_w, const float* __restrict__ k_w,
                         const float* __restrict__ v_w, const float* __restrict__ k_b,
                         const float* __restrict__ v_b, const float* __restrict__ a_rel,
                         const float* __restrict__ m_rel, const float* __restrict__ out_w,
                         u16* __restrict__ lin0T, u16* __restrict__ lin1T,
                         u16* __restrict__ qT, u16* __restrict__ aT,
                         u16* __restrict__ kfT, u16* __restrict__ vfT,
                         u16* __restrict__ owT,
                         float* __restrict__ bkf, float* __restrict__ bvf)
{
  const int tid = blockIdx.x * 256 + threadIdx.x;  // 0..65535 ; out layout [n][k]
  const int nn = tid >> 8, kk = tid & 255;
  switch (blockIdx.y) {
    case 0: lin0T[tid] = f2b(lin_w[kk * 256 + nn]); break;
    case 1: lin1T[tid] = f2b(lin_w[65536 + kk * 256 + nn]); break;
    case 2: qT[tid] = f2b(q_w[65536 + kk * 256 + nn]); break;
    case 3: aT[tid] = f2b(a_w[65536 + kk * 256 + nn]); break;
    case 4: {
      const int h = nn >> 5, e = nn & 31;
      float s = 0.f;
      for (int d = 0; d < 32; ++d) s += k_w[kk * 256 + h * 32 + d] * a_rel[(h * 32 + d) * 32 + e];
      kfT[tid] = f2b(s);
      if (kk == 0) {
        float sb = 0.f;
        for (int d = 0; d < 32; ++d) sb += k_b[h * 32 + d] * a_rel[(h * 32 + d) * 32 + e];
        bkf[nn] = sb;
      }
      break;
    }
    case 5: {
      const int h = nn >> 5, e = nn & 31;
      float s = 0.f;
      for (int d = 0; d < 32; ++d) s += v_w[kk * 256 + h * 32 + d] * m_rel[(h * 32 + d) * 32 + e];
      vfT[tid] = f2b(s);
      if (kk == 0) {
        float sb = 0.f;
        for (int d = 0; d < 32; ++d) sb += v_b[h * 32 + d] * m_rel[(h * 32 + d) * 32 + e];
        bvf[nn] = sb;
      }
      break;
    }
    default:
      if (tid < 4096) owT[tid] = f2b(out_w[kk * 16 + nn]);  // owT[n][k], n<16
      break;
  }
}

// ---------- bucket-CSR build for edge type 0 (src type 0 -> dst type 1) ----------
__global__ void scatter_k(const int* __restrict__ ei, int* __restrict__ cnt, int* __restrict__ srcl) {
  const int e = blockIdx.x * 256 + threadIdx.x;
  if (e >= NEDGE) return;
  const int src = ei[e];          // edge_index[0][0][e]
  const int dst = ei[NEDGE + e];  // edge_index[0][1][e]
  if ((unsigned)dst >= NNODES || (unsigned)src >= NNODES) return;
  const int pos = atomicAdd(&cnt[dst], 1);
  if (pos < DEGCAP) srcl[(size_t)dst * DEGCAP + pos] = src;
}

// ---------- fused attention softmax + aggregation + GELU; one wave per dst node ----------
__global__ void edge_agg_k(const u16* __restrict__ qb, const u16* __restrict__ krel,
                           const u16* __restrict__ vrel, const int* __restrict__ cnt,
                           const int* __restrict__ srcl, const float* __restrict__ prel,
                           u16* __restrict__ g)
{
  const int node = (blockIdx.x * blockDim.x + threadIdx.x) >> 6;
  if (node >= NNODES) return;
  const int lane = threadIdx.x & 63;
  const int hh = lane >> 3;                 // head
  const int off = hh * 32 + (lane & 7) * 4; // 4 dims per lane
  const float scale = prel[hh] * 0.17677669529663687f;  // p_rel[0][h] / sqrt(32)
  const uint2 qv = *(const uint2*)(qb + (size_t)node * 256 + off);
  const float q0 = blo2f(qv.x) * scale, q1 = bhi2f(qv.x) * scale;
  const float q2 = blo2f(qv.y) * scale, q3 = bhi2f(qv.y) * scale;
  int dg = cnt[node]; if (dg > DEGCAP) dg = DEGCAP;
  const int* sl = srcl + (size_t)node * DEGCAP;
  float den = 0.f, a0 = 0.f, a1 = 0.f, a2 = 0.f, a3 = 0.f;
  for (int i = 0; i < dg; ++i) {
    const int src = sl[i];
    const uint2 kv = *(const uint2*)(krel + (size_t)src * 256 + off);
    float p = q0 * blo2f(kv.x) + q1 * bhi2f(kv.x) + q2 * blo2f(kv.y) + q3 * bhi2f(kv.y);
    p += __shfl_xor(p, 1);
    p += __shfl_xor(p, 2);
    p += __shfl_xor(p, 4);           // 8-lane head-group reduce
    const float ex = __expf(p);      // no max-subtraction: |alpha| is O(1) here
    const uint2 vv = *(const uint2*)(vrel + (size_t)src * 256 + off);
    den += ex;
    a0 += ex * blo2f(vv.x); a1 += ex * bhi2f(vv.x);
    a2 += ex * blo2f(vv.y); a3 += ex * bhi2f(vv.y);
  }
  float r0 = 0.f, r1 = 0.f, r2 = 0.f, r3 = 0.f;
  if (dg > 0) {
    const float inv = 1.f / den;
    r0 = gelu_exact(a0 * inv); r1 = gelu_exact(a1 * inv);
    r2 = gelu_exact(a2 * inv); r3 = gelu_exact(a3 * inv);
  }
  uint2 gv;
  gv.x = (u32)f2b(r0) | ((u32)f2b(r1) << 16);
  gv.y = (u32)f2b(r2) | ((u32)f2b(r3) << 16);
  *(uint2*)(g + (size_t)node * 256 + off) = gv;
}

// ---------- streaming out GEMM: out[50000,16] = o[50000,256] @ owT^T + out_b (fp32) ----------
__launch_bounds__(256, 4)
__global__ void out_s(const u16* __restrict__ o, const u16* __restrict__ owT,
                      const float* __restrict__ ob, float* __restrict__ out)
{
  const int tid = threadIdx.x;
  const int lane = tid & 63;
  const int wave = tid >> 6;
  const int lr = lane & 15;
  const int lq = lane >> 4;
  const int w0 = blockIdx.x * 4 + wave;
  const int ws = gridDim.x * 4;

  bh8 bw[8];
  {
    const u16* bp = owT + (size_t)lr * 256 + lq * 8;
#pragma unroll
    for (int ks = 0; ks < 8; ++ks) bw[ks] = *(const bh8*)(bp + ks * 32);
  }
  const float bv = ob[lr];

  const u16* ah = o + (size_t)w0 * 4096 + (size_t)lr * 256 + lq * 8;
  const size_t tstep = (size_t)ws * 4096;
  bh8 ab[8];
#pragma unroll
  for (int ks = 0; ks < 8; ++ks) ab[ks] = *(const bh8*)(ah + ks * 32);

  for (int t = w0; t < NT; t += ws) {
    if (t + ws < NT) ah += tstep;
    f32x4 acc = {0.f, 0.f, 0.f, 0.f};
#pragma unroll
    for (int ks = 0; ks < 8; ++ks) {
      acc = __builtin_amdgcn_mfma_f32_16x16x32_bf16(ab[ks], bw[ks], acc, 0, 0, 0);
      ab[ks] = *(const bh8*)(ah + ks * 32);
    }
#pragma unroll
    for (int r = 0; r < 4; ++r)
      out[((size_t)t * 16 + lq * 4 + r) * 16 + lr] = acc[r] + bv;
  }
}

extern "C" void kernel_launch(void* const* d_in, const int* in_sizes, int n_in,
                              void* d_out, int out_size, void* d_ws, size_t ws_size,
                              hipStream_t stream)
{
  const float* x     = (const float*)d_in[0];
  const int*   ei    = (const int*)d_in[1];
  const float* lin_w = (const float*)d_in[2];
  const float* lin_b = (const float*)d_in[3];
  const float* k_w   = (const float*)d_in[4];
  const float* k_b   = (const float*)d_in[5];
  const float* q_w   = (const float*)d_in[6];
  const float* q_b   = (const float*)d_in[7];
  const float* v_w   = (const float*)d_in[8];
  const float* v_b   = (const float*)d_in[9];
  const float* a_w   = (const float*)d_in[10];
  const float* a_b   = (const float*)d_in[11];
  const float* skipv = (const float*)d_in[12];
  const float* a_rel = (const float*)d_in[13];
  const float* m_rel = (const float*)d_in[14];
  const float* p_rel = (const float*)d_in[15];
  const float* out_w = (const float*)d_in[16];
  const float* out_b = (const float*)d_in[17];
  char* ws = (char*)d_ws;

  // workspace layout (bytes); h0 region reused for obuf after it dies
  u16*  h0    = (u16*)(ws + 0);              // 25.6 MB (dead after GEMM-B)
  u16*  h1    = (u16*)(ws + 25600000);       // 25.6 MB (alive till blend)
  u16*  qb    = (u16*)(ws + 51200000);
  u16*  gbuf  = (u16*)(ws + 76800000);
  u16*  krel  = (u16*)(ws + 102400000);
  u16*  vrel  = (u16*)(ws + 128000000);
  u16*  obuf  = (u16*)(ws + 0);              // reuse h0 region (bf16 o)
  char* W     = ws + 153600000;
  u16*  lin0T = (u16*)(W + 0);
  u16*  lin1T = (u16*)(W + 131072);
  u16*  qT    = (u16*)(W + 2 * 131072);
  u16*  aT    = (u16*)(W + 3 * 131072);
  u16*  kfT   = (u16*)(W + 4 * 131072);
  u16*  vfT   = (u16*)(W + 5 * 131072);
  u16*  owT   = (u16*)(W + 6 * 131072);      // 8 KB used
  float* bkf  = (float*)(W + 6 * 131072 + 8192);
  float* bvf  = (float*)(W + 6 * 131072 + 9216);
  int*  cnt   = (int*)(W + 6 * 131072 + 10240);
  int*  srcl  = (int*)(W + 6 * 131072 + 10240 + 200000);   // 12.8 MB

  hipMemsetAsync(cnt, 0, NNODES * sizeof(int), stream);
  prep_w_k<<<dim3(256, 7), 256, 0, stream>>>(lin_w, q_w, a_w, k_w, v_w, k_b, v_b,
                                             a_rel, m_rel, out_w,
                                             lin0T, lin1T, qT, aT, kfT, vfT, owT, bkf, bvf);
  scatter_k<<<(NEDGE + 255) / 256, 256, 0, stream>>>(ei, cnt, srcl);

  {  // h[t] = relu(x[t] @ lin_w[t] + lin_b[t]) ; fp32 A converted in-registers
    GArg a0{x, lin0T, lin_b, h0};
    GArg a1{x + (size_t)NNODES * 256, lin1T, lin_b + 256, h1};
    gemm_s<0><<<dim3(320, 2, 2), 256, 0, stream>>>(a0, a1, a0, nullptr, nullptr);
  }
  {  // q1 = h1@q_w1+b ; krel = h0@(k_w0*a_rel0)+b' ; vrel = h0@(v_w0*m_rel0)+b'
    GArg a0{h1, qT, q_b + 256, qb};
    GArg a1{h0, kfT, bkf, krel};
    GArg a2{h0, vfT, bvf, vrel};
    gemm_s<1><<<dim3(320, 2, 3), 256, 0, stream>>>(a0, a1, a2, nullptr, nullptr);
  }
  edge_agg_k<<<12500, 256, 0, stream>>>(qb, krel, vrel, cnt, srcl, p_rel, gbuf);
  {  // o = beta*(gelu(agg)@a_w1 + a_b1) + (1-beta)*h1, bf16 out
    GArg a0{gbuf, aT, a_b + 256, obuf};
    gemm_s<2><<<dim3(320, 2, 1), 256, 0, stream>>>(a0, a0, a0, h1, skipv + 1);
  }
  out_s<<<200, 256, 0, stream>>>(obuf, owT, out_b, (float*)d_out);
}

// Round 7
// 362.056 us; speedup vs baseline: 1.4437x; 1.2982x over previous
//
#include <hip/hip_runtime.h>
#include <hip/hip_bf16.h>

using u16 = unsigned short;
using u32 = unsigned int;

#define NNODES 50000
#define NEDGE  200000
#define DEGCAP 64
#define NT     3125   // 50000 / 16 row-tiles

// ---------- bf16 helpers ----------
__device__ __forceinline__ float blo2f(u32 u) { u32 v = u << 16; float f; __builtin_memcpy(&f, &v, 4); return f; }
__device__ __forceinline__ float bhi2f(u32 u) { u32 v = u & 0xffff0000u; float f; __builtin_memcpy(&f, &v, 4); return f; }
__device__ __forceinline__ float b2f(u16 u) { u32 v = ((u32)u) << 16; float f; __builtin_memcpy(&f, &v, 4); return f; }
__device__ __forceinline__ u16 f2b(float f) {
  __hip_bfloat16 h = __float2bfloat16(f);   // RNE
  u16 r; __builtin_memcpy(&r, &h, 2); return r;
}
__device__ __forceinline__ float gelu_exact(float x) {
  return 0.5f * x * (1.f + erff(x * 0.70710678118654752f));
}

// ---------- async global->LDS (16B per lane), consecutive-lane coalesced ----------
__device__ __forceinline__ void gload16(const void* gp, void* lp) {
  __builtin_amdgcn_global_load_lds(
      (__attribute__((address_space(1))) u32*)(const_cast<void*>(gp)),
      (__attribute__((address_space(3))) u32*)lp, 16, 0, 0);
}

// Full vmem drain + compiler memory fence: all global_load_lds deposits visible.
__device__ __forceinline__ void wait_vm0() {
  asm volatile("s_waitcnt vmcnt(0)" ::: "memory");
}

typedef __bf16 bh8 __attribute__((ext_vector_type(8)));
typedef float f32x4 __attribute__((ext_vector_type(4)));

struct GArg { const u16* A; const u16* B; const float* bias; u16* C; };

// Stage one 16-row x 256-col bf16 A-tile (8 KB) into a wave-private LDS buffer.
// Global chunk index XOR-swizzled by (row&7): element (r,chunk q) lands at LDS
// u16-offset r*256 + (q^(r&7))*8. Each instruction covers a contiguous 1 KB
// global region (coalesced) and a contiguous 1 KB LDS region (wave-uniform
// base + lane*16B, as the HW requires).
__device__ __forceinline__ void stage_tile(const u16* At, u16* buf, int lane) {
#pragma unroll
  for (int i = 0; i < 8; ++i) {
    const int row = i * 2 + (lane >> 5);
    const int c   = (lane & 31) ^ (row & 7);
    gload16(At + (size_t)row * 256 + c * 8, buf + i * 512 + lane * 8);
  }
}

// ---------- streaming GEMM: C[50000,256] = A[50000,256] @ B^T + bias ----------
// A bf16 [m][k]; B bf16 [n][k] register-resident per wave (32-col strip).
// COVERAGE: colbase = blockIdx.y*32 (wave-INDEPENDENT); row-tiles per-wave
// (blockIdx.x*4+wave, step gridDim.x*4) -> every (tile,strip) pair exactly once.
// Wave-private single-buffer staging: stage -> vmcnt(0) -> compute. No barriers.
// MODE 0: relu. MODE 1: bias only. MODE 2: skip-blend with hbl. All bf16 out.
template <int MODE>
__launch_bounds__(256, 3)
__global__ void gemm_v7(GArg g0, GArg g1, GArg g2,
                        const u16* __restrict__ hbl, const float* __restrict__ skipv)
{
  GArg ga = (blockIdx.z == 0) ? g0 : ((blockIdx.z == 1) ? g1 : g2);
  const int tid = threadIdx.x;
  const int lane = tid & 63;
  const int wave = tid >> 6;
  const int lr = lane & 15;
  const int lq = lane >> 4;
  const int colbase = blockIdx.y * 32;          // same strip for all 4 waves

  __shared__ alignas(16) u16 lds[4][4096];      // 32 KB staging: 4 waves x 8 KB
  __shared__ alignas(16) u16 pat[4][640];       // 5 KB epilogue patches (separate!)
  u16* buf = &lds[wave][0];
  u16* wl  = &pat[wave][0];

  // --- B strip (K=256 for 32 cols) into registers, loaded once ---
  bh8 B0[8], B1[8];
  {
    const u16* bp0 = ga.B + (size_t)(colbase + lr) * 256 + lq * 8;
    const u16* bp1 = bp0 + 16 * 256;
#pragma unroll
    for (int ks = 0; ks < 8; ++ks) {
      B0[ks] = *(const bh8*)(bp0 + ks * 32);
      B1[ks] = *(const bh8*)(bp1 + ks * 32);
    }
  }
  const float bias0 = ga.bias[colbase + lr];
  const float bias1 = ga.bias[colbase + 16 + lr];
  float beta = 0.f, omb = 0.f;
  if (MODE == 2) { beta = 1.f / (1.f + __expf(-skipv[0])); omb = 1.f - beta; }

  // fragment read offsets (swizzle-aware): element (lr, chunk ks*4+lq)
  int foff[8];
#pragma unroll
  for (int ks = 0; ks < 8; ++ks)
    foff[ks] = lr * 256 + (((ks * 4 + lq) ^ (lr & 7)) * 8);

  const int wt0 = blockIdx.x * 4 + wave;
  const int wts = gridDim.x * 4;

  for (int t = wt0; t < NT; t += wts) {
    stage_tile(ga.A + (size_t)t * 4096, buf, lane);
    wait_vm0();                      // tile fully resident in LDS

    bh8 ab[8];
#pragma unroll
    for (int ks = 0; ks < 8; ++ks) ab[ks] = *(const bh8*)(buf + foff[ks]);

    f32x4 acc0 = {0.f, 0.f, 0.f, 0.f};
    f32x4 acc1 = {0.f, 0.f, 0.f, 0.f};
#pragma unroll
    for (int ks = 0; ks < 8; ++ks) {
      acc0 = __builtin_amdgcn_mfma_f32_16x16x32_bf16(ab[ks], B0[ks], acc0, 0, 0, 0);
      acc1 = __builtin_amdgcn_mfma_f32_16x16x32_bf16(ab[ks], B1[ks], acc1, 0, 0, 0);
    }

    // --- epilogue: acc -> dedicated per-wave LDS patch -> coalesced 32-col store ---
#pragma unroll
    for (int r = 0; r < 4; ++r) {
      float v0 = acc0[r] + bias0;
      float v1 = acc1[r] + bias1;
      if (MODE == 0) { v0 = fmaxf(v0, 0.f); v1 = fmaxf(v1, 0.f); }
      wl[(lq * 4 + r) * 40 + lr]      = f2b(v0);
      wl[(lq * 4 + r) * 40 + 16 + lr] = f2b(v1);
    }
    const int rrow = lane >> 2, rseg = lane & 3;
    const uint4 pv = *(const uint4*)(wl + rrow * 40 + rseg * 8);   // lgkm wait auto
    const size_t cb = ((size_t)t * 16 + rrow) * 256 + colbase + rseg * 8;
    if (MODE == 2) {
      const uint4 hv = *(const uint4*)(hbl + cb);
      const u32 p[4] = {pv.x, pv.y, pv.z, pv.w};
      const u32 h[4] = {hv.x, hv.y, hv.z, hv.w};
      u32 o[4];
#pragma unroll
      for (int j = 0; j < 4; ++j) {
        const float a0 = blo2f(p[j]), a1 = bhi2f(p[j]);
        const float h0 = blo2f(h[j]), h1 = bhi2f(h[j]);
        o[j] = (u32)f2b(beta * a0 + omb * h0) | ((u32)f2b(beta * a1 + omb * h1) << 16);
      }
      uint4 ov; ov.x = o[0]; ov.y = o[1]; ov.z = o[2]; ov.w = o[3];
      *(uint4*)(ga.C + cb) = ov;
    } else {
      *(uint4*)(ga.C + cb) = pv;
    }
  }
}

// ---------- fp32 -> bf16 conversion of x (streaming) ----------
__global__ void cvt_x_k(const float* __restrict__ x, u16* __restrict__ xb) {
  const int id = blockIdx.x * 256 + threadIdx.x;   // 8 floats per thread
  if (id >= (2 * NNODES * 256) / 8) return;
  const float4 a = ((const float4*)x)[id * 2];
  const float4 b = ((const float4*)x)[id * 2 + 1];
  uint4 o;
  o.x = (u32)f2b(a.x) | ((u32)f2b(a.y) << 16);
  o.y = (u32)f2b(a.z) | ((u32)f2b(a.w) << 16);
  o.z = (u32)f2b(b.x) | ((u32)f2b(b.y) << 16);
  o.w = (u32)f2b(b.z) | ((u32)f2b(b.w) << 16);
  ((uint4*)xb)[id] = o;
}

// ---------- weight prep: transpose->bf16, fold a_rel/m_rel into k/v weights, out_w^T ----------
__global__ void prep_w_k(const float* __restrict__ lin_w, const float* __restrict__ q_w,
                         const float* __restrict__ a_w, const float* __restrict__ k_w,
                         const float* __restrict__ v_w, const float* __restrict__ k_b,
                         const float* __restrict__ v_b, const float* __restrict__ a_rel,
                         const float* __restrict__ m_rel, const float* __restrict__ out_w,
                         u16* __restrict__ lin0T, u16* __restrict__ lin1T,
                         u16* __restrict__ qT, u16* __restrict__ aT,
                         u16* __restrict__ kfT, u16* __restrict__ vfT,
                         u16* __restrict__ owT,
                         float* __restrict__ bkf, float* __restrict__ bvf)
{
  const int tid = blockIdx.x * 256 + threadIdx.x;  // 0..65535 ; out layout [n][k]
  const int nn = tid >> 8, kk = tid & 255;
  switch (blockIdx.y) {
    case 0: lin0T[tid] = f2b(lin_w[kk * 256 + nn]); break;
    case 1: lin1T[tid] = f2b(lin_w[65536 + kk * 256 + nn]); break;
    case 2: qT[tid] = f2b(q_w[65536 + kk * 256 + nn]); break;
    case 3: aT[tid] = f2b(a_w[65536 + kk * 256 + nn]); break;
    case 4: {
      const int h = nn >> 5, e = nn & 31;
      float s = 0.f;
      for (int d = 0; d < 32; ++d) s += k_w[kk * 256 + h * 32 + d] * a_rel[(h * 32 + d) * 32 + e];
      kfT[tid] = f2b(s);
      if (kk == 0) {
        float sb = 0.f;
        for (int d = 0; d < 32; ++d) sb += k_b[h * 32 + d] * a_rel[(h * 32 + d) * 32 + e];
        bkf[nn] = sb;
      }
      break;
    }
    case 5: {
      const int h = nn >> 5, e = nn & 31;
      float s = 0.f;
      for (int d = 0; d < 32; ++d) s += v_w[kk * 256 + h * 32 + d] * m_rel[(h * 32 + d) * 32 + e];
      vfT[tid] = f2b(s);
      if (kk == 0) {
        float sb = 0.f;
        for (int d = 0; d < 32; ++d) sb += v_b[h * 32 + d] * m_rel[(h * 32 + d) * 32 + e];
        bvf[nn] = sb;
      }
      break;
    }
    default:
      if (tid < 4096) owT[tid] = f2b(out_w[kk * 16 + nn]);  // owT[n][k], n<16
      break;
  }
}

// ---------- bucket-CSR build for edge type 0 (src type 0 -> dst type 1) ----------
__global__ void scatter_k(const int* __restrict__ ei, int* __restrict__ cnt, int* __restrict__ srcl) {
  const int e = blockIdx.x * 256 + threadIdx.x;
  if (e >= NEDGE) return;
  const int src = ei[e];          // edge_index[0][0][e]
  const int dst = ei[NEDGE + e];  // edge_index[0][1][e]
  if ((unsigned)dst >= NNODES || (unsigned)src >= NNODES) return;
  const int pos = atomicAdd(&cnt[dst], 1);
  if (pos < DEGCAP) srcl[(size_t)dst * DEGCAP + pos] = src;
}

// ---------- fused attention softmax + aggregation + GELU; one wave per dst node ----------
__global__ void edge_agg_k(const u16* __restrict__ qb, const u16* __restrict__ krel,
                           const u16* __restrict__ vrel, const int* __restrict__ cnt,
                           const int* __restrict__ srcl, const float* __restrict__ prel,
                           u16* __restrict__ g)
{
  const int node = (blockIdx.x * blockDim.x + threadIdx.x) >> 6;
  if (node >= NNODES) return;
  const int lane = threadIdx.x & 63;
  const int hh = lane >> 3;                 // head
  const int off = hh * 32 + (lane & 7) * 4; // 4 dims per lane
  const float scale = prel[hh] * 0.17677669529663687f;  // p_rel[0][h] / sqrt(32)
  const uint2 qv = *(const uint2*)(qb + (size_t)node * 256 + off);
  const float q0 = blo2f(qv.x) * scale, q1 = bhi2f(qv.x) * scale;
  const float q2 = blo2f(qv.y) * scale, q3 = bhi2f(qv.y) * scale;
  int dg = cnt[node]; if (dg > DEGCAP) dg = DEGCAP;
  const int* sl = srcl + (size_t)node * DEGCAP;
  float den = 0.f, a0 = 0.f, a1 = 0.f, a2 = 0.f, a3 = 0.f;
  for (int i = 0; i < dg; ++i) {
    const int src = sl[i];
    const uint2 kv = *(const uint2*)(krel + (size_t)src * 256 + off);
    float p = q0 * blo2f(kv.x) + q1 * bhi2f(kv.x) + q2 * blo2f(kv.y) + q3 * bhi2f(kv.y);
    p += __shfl_xor(p, 1);
    p += __shfl_xor(p, 2);
    p += __shfl_xor(p, 4);           // 8-lane head-group reduce
    const float ex = __expf(p);      // no max-subtraction: |alpha| is O(1) here
    const uint2 vv = *(const uint2*)(vrel + (size_t)src * 256 + off);
    den += ex;
    a0 += ex * blo2f(vv.x); a1 += ex * bhi2f(vv.x);
    a2 += ex * blo2f(vv.y); a3 += ex * bhi2f(vv.y);
  }
  float r0 = 0.f, r1 = 0.f, r2 = 0.f, r3 = 0.f;
  if (dg > 0) {
    const float inv = 1.f / den;
    r0 = gelu_exact(a0 * inv); r1 = gelu_exact(a1 * inv);
    r2 = gelu_exact(a2 * inv); r3 = gelu_exact(a3 * inv);
  }
  uint2 gv;
  gv.x = (u32)f2b(r0) | ((u32)f2b(r1) << 16);
  gv.y = (u32)f2b(r2) | ((u32)f2b(r3) << 16);
  *(uint2*)(g + (size_t)node * 256 + off) = gv;
}

// ---------- out GEMM, same single-buffer style: out[50000,16] = o @ owT^T + out_b ----------
// Covers all 16 output cols per tile (lr); per-wave row tiles -> full coverage.
__launch_bounds__(256, 3)
__global__ void out_v7(const u16* __restrict__ o, const u16* __restrict__ owT,
                       const float* __restrict__ ob, float* __restrict__ out)
{
  const int tid = threadIdx.x;
  const int lane = tid & 63;
  const int wave = tid >> 6;
  const int lr = lane & 15;
  const int lq = lane >> 4;

  __shared__ alignas(16) u16 lds[4][4096];
  u16* buf = &lds[wave][0];

  bh8 bw[8];
  {
    const u16* bp = owT + (size_t)lr * 256 + lq * 8;
#pragma unroll
    for (int ks = 0; ks < 8; ++ks) bw[ks] = *(const bh8*)(bp + ks * 32);
  }
  const float bv = ob[lr];

  int foff[8];
#pragma unroll
  for (int ks = 0; ks < 8; ++ks)
    foff[ks] = lr * 256 + (((ks * 4 + lq) ^ (lr & 7)) * 8);

  const int wt0 = blockIdx.x * 4 + wave;
  const int wts = gridDim.x * 4;

  for (int t = wt0; t < NT; t += wts) {
    stage_tile(o + (size_t)t * 4096, buf, lane);
    wait_vm0();
    f32x4 acc = {0.f, 0.f, 0.f, 0.f};
#pragma unroll
    for (int ks = 0; ks < 8; ++ks)
      acc = __builtin_amdgcn_mfma_f32_16x16x32_bf16(*(const bh8*)(buf + foff[ks]), bw[ks], acc, 0, 0, 0);
#pragma unroll
    for (int r = 0; r < 4; ++r)
      out[((size_t)t * 16 + lq * 4 + r) * 16 + lr] = acc[r] + bv;
  }
}

extern "C" void kernel_launch(void* const* d_in, const int* in_sizes, int n_in,
                              void* d_out, int out_size, void* d_ws, size_t ws_size,
                              hipStream_t stream)
{
  const float* x     = (const float*)d_in[0];
  const int*   ei    = (const int*)d_in[1];
  const float* lin_w = (const float*)d_in[2];
  const float* lin_b = (const float*)d_in[3];
  const float* k_w   = (const float*)d_in[4];
  const float* k_b   = (const float*)d_in[5];
  const float* q_w   = (const float*)d_in[6];
  const float* q_b   = (const float*)d_in[7];
  const float* v_w   = (const float*)d_in[8];
  const float* v_b   = (const float*)d_in[9];
  const float* a_w   = (const float*)d_in[10];
  const float* a_b   = (const float*)d_in[11];
  const float* skipv = (const float*)d_in[12];
  const float* a_rel = (const float*)d_in[13];
  const float* m_rel = (const float*)d_in[14];
  const float* p_rel = (const float*)d_in[15];
  const float* out_w = (const float*)d_in[16];
  const float* out_b = (const float*)d_in[17];
  char* ws = (char*)d_ws;

  // workspace layout (bytes), regions reused as lifetimes end:
  u16*  xb    = (u16*)(ws + 0);              // 51.2 MB; dead after lin GEMM
  u16*  h0    = (u16*)(ws + 51200000);       // dead after mid GEMM
  u16*  h1    = (u16*)(ws + 76800000);       // alive till blend
  u16*  qb    = (u16*)(ws + 102400000);      // dead after edge_agg
  u16*  gbuf  = (u16*)(ws + 128000000);      // dead after blend
  u16*  krel  = (u16*)(ws + 0);              // reuse xb (dead after edge_agg)
  u16*  vrel  = (u16*)(ws + 25600000);       // reuse xb upper half
  u16*  obuf  = (u16*)(ws + 0);              // reuse krel region after edge_agg
  char* W     = ws + 153600000;
  u16*  lin0T = (u16*)(W + 0);
  u16*  lin1T = (u16*)(W + 131072);
  u16*  qT    = (u16*)(W + 2 * 131072);
  u16*  aT    = (u16*)(W + 3 * 131072);
  u16*  kfT   = (u16*)(W + 4 * 131072);
  u16*  vfT   = (u16*)(W + 5 * 131072);
  u16*  owT   = (u16*)(W + 6 * 131072);      // 8 KB used
  float* bkf  = (float*)(W + 6 * 131072 + 8192);
  float* bvf  = (float*)(W + 6 * 131072 + 9216);
  int*  cnt   = (int*)(W + 6 * 131072 + 10240);
  int*  srcl  = (int*)(W + 6 * 131072 + 10240 + 200000);   // 12.8 MB

  hipMemsetAsync(cnt, 0, NNODES * sizeof(int), stream);
  prep_w_k<<<dim3(256, 7), 256, 0, stream>>>(lin_w, q_w, a_w, k_w, v_w, k_b, v_b,
                                             a_rel, m_rel, out_w,
                                             lin0T, lin1T, qT, aT, kfT, vfT, owT, bkf, bvf);
  scatter_k<<<(NEDGE + 255) / 256, 256, 0, stream>>>(ei, cnt, srcl);
  cvt_x_k<<<12500, 256, 0, stream>>>(x, xb);

  {  // h[t] = relu(x[t] @ lin_w[t] + lin_b[t])
    GArg a0{xb, lin0T, lin_b, h0};
    GArg a1{xb + (size_t)NNODES * 256, lin1T, lin_b + 256, h1};
    gemm_v7<0><<<dim3(48, 8, 2), 256, 0, stream>>>(a0, a1, a0, nullptr, nullptr);
  }
  {  // q1 = h1@q_w1+b ; krel = h0@(k_w0*a_rel0)+b' ; vrel = h0@(v_w0*m_rel0)+b'
    GArg a0{h1, qT, q_b + 256, qb};
    GArg a1{h0, kfT, bkf, krel};
    GArg a2{h0, vfT, bvf, vrel};
    gemm_v7<1><<<dim3(32, 8, 3), 256, 0, stream>>>(a0, a1, a2, nullptr, nullptr);
  }
  edge_agg_k<<<12500, 256, 0, stream>>>(qb, krel, vrel, cnt, srcl, p_rel, gbuf);
  {  // o = beta*(gelu(agg)@a_w1 + a_b1) + (1-beta)*h1, bf16 out
    GArg a0{gbuf, aT, a_b + 256, obuf};
    gemm_v7<2><<<dim3(96, 8, 1), 256, 0, stream>>>(a0, a0, a0, h1, skipv + 1);
  }
  out_v7<<<192, 256, 0, stream>>>(obuf, owT, out_b, (float*)d_out);
}